// Round 20
// baseline (203.183 us; speedup 1.0000x reference)
//
#include <hip/hip_runtime.h>
#include <math.h>

#define TSTEPS 128
#define NFEAT 16

typedef __fp16 f16;
typedef __fp16 f16x2 __attribute__((ext_vector_type(2)));
typedef __fp16 f16x8 __attribute__((ext_vector_type(8)));
typedef float f32x2 __attribute__((ext_vector_type(2)));
typedef float f32x4 __attribute__((ext_vector_type(4)));

union F8 { f16x8 v; f16x2 h[4]; };

__device__ __forceinline__ float frcp(float x){ return __builtin_amdgcn_rcpf(x); }
__device__ __forceinline__ float frsq(float x){ return __builtin_amdgcn_rsqf(x); }
__device__ __forceinline__ float bperm(int addr, float v){
    return __int_as_float(__builtin_amdgcn_ds_bpermute(addr, __float_as_int(v)));
}
__device__ __forceinline__ f16x2 pkrtz(float a, float b){
    return __builtin_amdgcn_cvt_pkrtz(a, b);
}
__device__ __forceinline__ float dpp_xor1(float v){
    return __int_as_float(__builtin_amdgcn_update_dpp(0, __float_as_int(v), 0xB1, 0xF, 0xF, true));
}
__device__ __forceinline__ float dpp_xor2(float v){
    return __int_as_float(__builtin_amdgcn_update_dpp(0, __float_as_int(v), 0x4E, 0xF, 0xF, true));
}
__device__ __forceinline__ float swz_xor4(float v){
    return __int_as_float(__builtin_amdgcn_ds_swizzle(__float_as_int(v), 0x101F));
}
__device__ __forceinline__ float swz_xor8(float v){
    return __int_as_float(__builtin_amdgcn_ds_swizzle(__float_as_int(v), 0x201F));
}
template<int MASK> __device__ __forceinline__ float pshfl(float v){
    if constexpr (MASK == 1) return dpp_xor1(v);
    else if constexpr (MASK == 2) return dpp_xor2(v);
    else if constexpr (MASK == 4) return swz_xor4(v);
    else return swz_xor8(v);
}
__device__ __forceinline__ void cfence(){ __asm__ __volatile__("" ::: "memory"); }

__device__ __forceinline__ float sigm(float x){ return frcp(1.f + __expf(-x)); }
__device__ __forceinline__ float tanh_f(float x){ return 1.f - 2.f * frcp(__expf(2.f*x) + 1.f); }

// packed complex multiply (v_pk_mul_f32 + v_pk_fma_f32 candidates)
__device__ __forceinline__ f32x2 cmul(f32x2 a, f32x2 b){
    f32x2 bs = {b.y, b.x};
    f32x2 ar = {a.x, a.x};
    f32x2 ai = {-a.y, a.y};
    return ar*b + ai*bs;
}

// merged RZ*RY*RX on wire I (prologue / U-construction only)
template<int I>
__device__ __forceinline__ void gate_step(float &re, float &im,
                                          const float* gt, int ai, int loff){
    const float4 g = *(const float4*)((const char*)gt + ai + loff);
    float pre = pshfl<(1 << I)>(re);
    float pim = pshfl<(1 << I)>(im);
    float nre = g.x*re - g.y*im + g.z*pre - g.w*pim;
    float nim = g.x*im + g.y*re + g.z*pim + g.w*pre;
    re = nre; im = nim;
}

// fused factor products: F(0) = (c1c2, -c1s2), F(1) = (s1c2, s1s2); 3 trans
__device__ __forceinline__ void factors(float u, float &F0r, float &F0i,
                                        float &F1r, float &F1i){
    float u2  = u * u;
    float ca1 = frsq(1.f + u2);
    float ca2 = frsq(1.f + u2*u2);
    float x1  = (1.f + ca1) * 0.5f;
    float x2  = (1.f + ca2) * 0.5f;
    float x12 = x1 * x2;
    float t   = frsq(x12);
    float a1  = u  * ca1 * 0.5f;
    float a2  = u2 * ca2 * 0.5f;
    F0r = x12 * t;
    F0i = -(a2 * x1 * t);
    F1r = a1 * x2 * t;
    F1i = a1 * a2 * t;
}

__device__ __forceinline__ void write_F(float* bc, int e, int s,
                                        float F0r, float F0i, float F1r, float F1i){
    float4 w;
    w.x = F0r; w.y = F0i; w.z = F1r; w.w = F1i;
    *(float4*)(bc + e*20 + s*4) = w;
}

__device__ __forceinline__ void build_psi(const float* bc, int e, int sm1, int sm2,
                                          F8 &bp){
    const float4 w0 = *(const float4*)(bc + e*20);
    const float4 w1 = *(const float4*)(bc + e*20 + 4);
    const f32x2 F2 = *(const f32x2*)(bc + e*20 + 8  + sm1*2);
    const f32x2 F3 = *(const f32x2*)(bc + e*20 + 12 + sm2*2);
    f32x2 w00 = {w0.x, w0.y}, w01 = {w0.z, w0.w};
    f32x2 w10 = {w1.x, w1.y}, w11 = {w1.z, w1.w};
    f32x2 pre = cmul(F2, F3);
    f32x2 P0 = cmul(pre, w10);
    f32x2 P1 = cmul(pre, w11);
    f32x2 a0 = cmul(P0, w00);
    f32x2 a1 = cmul(P0, w01);
    f32x2 a2 = cmul(P1, w00);
    f32x2 a3 = cmul(P1, w01);
    bp.h[0] = pkrtz(a0.x, a0.y);
    bp.h[1] = pkrtz(a1.x, a1.y);
    bp.h[2] = pkrtz(a2.x, a2.y);
    bp.h[3] = pkrtz(a3.x, a3.y);
}

__device__ __forceinline__ F8 pack_P(const f32x4 &reE, const f32x4 &imE,
                                     const f32x4 &reO, const f32x4 &imO){
    f32x4 pE = reE*reE + imE*imE;
    f32x4 pO = reO*reO + imO*imO;
    F8 b;
    b.h[0] = pkrtz(pE[0], pE[1]);
    b.h[1] = pkrtz(pE[2], pE[3]);
    b.h[2] = pkrtz(pO[0], pO[1]);
    b.h[3] = pkrtz(pO[2], pO[3]);
    return b;
}

__device__ __forceinline__ float sel4(float a0, float a1, float a2, float a3, int s){
    float lo = (s & 1) ? a1 : a0;
    float hi = (s & 1) ? a3 : a2;
    return (s & 2) ? hi : lo;
}

__global__ void __launch_bounds__(64, 1) qlstm_kernel(
    const float* __restrict__ x, const float* __restrict__ phi,
    const float* __restrict__ Wd, const float* __restrict__ bd,
    float* __restrict__ out, int B)
{
    __shared__ __align__(16) float gtab[384];
    __shared__ __align__(16) float ldsf[3072];   // U[k][m][c]; factor regions alias it
    const int BCa = 0;     // group A factor region (aliases U k=0, prologue-only)
    const int BCb = 512;   // group B factor region (aliases U k=1)

    const int tid  = threadIdx.x;
    const int lane = tid & 63;
    const int m    = lane & 15;
    const int grp  = lane >> 4;

    // ---------------- prologue: merged-gate table ----------------------------
    for (int idx = tid; idx < 96; idx += 64){
        int i = idx & 3, l = (idx >> 2) & 1, bb = (idx >> 3) & 1, k = idx >> 4;
        const float* pp = phi + (k*2 + l)*12 + 3*i;
        float ca, sa, cb, sb, cg, sg;
        __sincosf(0.5f*pp[0], &sa, &ca);
        __sincosf(0.5f*pp[1], &sb, &cb);
        __sincosf(0.5f*pp[2], &sg, &cg);
        float Ar, Ai, Br, Bi;
        if (bb == 0){
            float m00r = cb*ca,  m00i = sb*sa;
            float m01r = -sb*ca, m01i = -cb*sa;
            Ar = m00r*cg + m00i*sg;  Ai = m00i*cg - m00r*sg;
            Br = m01r*cg + m01i*sg;  Bi = m01i*cg - m01r*sg;
        } else {
            float m10r = sb*ca, m10i = -cb*sa;
            float m11r = cb*ca, m11i = -sb*sa;
            Ar = m11r*cg - m11i*sg;  Ai = m11i*cg + m11r*sg;
            Br = m10r*cg - m10i*sg;  Bi = m10i*cg + m10r*sg;
        }
        float* dst = gtab + (l*4 + i)*48 + (k*2 + bb)*4;
        dst[0] = Ar; dst[1] = Ai; dst[2] = Br; dst[3] = Bi;
    }
    __syncthreads();

    const int n0 = m & 1, n1 = (m >> 1) & 1, n2 = (m >> 2) & 1, n3 = (m >> 3) & 1;
    const int pm = (n0^n1^n2) | ((n0^n2^n3) << 1) | ((n0^n1^n3) << 2) | ((n0^n1) << 3);
    const int bpaddr = ((lane & 48) | pm) * 4;

    // ---------------- prologue: build U_k columns via shuffle circuit --------
    for (int k = 0; k < 6; ++k){
        int ga0 = 0*192 + k*32 + ((m >> 0) & 1)*16;
        int ga1 = 1*192 + k*32 + ((m >> 1) & 1)*16;
        int ga2 = 2*192 + k*32 + ((m >> 2) & 1)*16;
        int ga3 = 3*192 + k*32 + ((m >> 3) & 1)*16;
        for (int cb = 0; cb < 4; ++cb){
            int c = cb*4 + grp;
            float re = (pm == c) ? 1.f : 0.f;
            float im = 0.f;
            gate_step<0>(re, im, gtab, ga0, 0);   gate_step<1>(re, im, gtab, ga1, 0);
            gate_step<2>(re, im, gtab, ga2, 0);   gate_step<3>(re, im, gtab, ga3, 0);
            re = bperm(bpaddr, re);
            im = bperm(bpaddr, im);
            gate_step<0>(re, im, gtab, ga0, 768); gate_step<1>(re, im, gtab, ga1, 768);
            gate_step<2>(re, im, gtab, ga2, 768); gate_step<3>(re, im, gtab, ga3, 768);
            float2* dst = (float2*)&ldsf[k*512 + m*32 + c*2];
            *dst = make_float2(re, im);
        }
    }
    __syncthreads();

    // ---------------- main layout: lane = (e, s); wave = 2 groups of 16 elems
    const int e = lane & 15;
    const int s = lane >> 4;
    const int sm1 = s & 1, sm2 = s >> 1;
    const int ecol = e & 3;

    // Shared A-fragments (element-independent)
    F8 are[6], aim[6];
    #pragma unroll
    for (int k = 0; k < 6; ++k){
        const float* ub = &ldsf[k*512 + e*32 + s*8];
        float4 u01 = *(const float4*)ub;
        float4 u23 = *(const float4*)(ub + 4);
        are[k].h[0] = (f16x2){(f16)u01.x, (f16)(-u01.y)};
        are[k].h[1] = (f16x2){(f16)u01.z, (f16)(-u01.w)};
        are[k].h[2] = (f16x2){(f16)u23.x, (f16)(-u23.y)};
        are[k].h[3] = (f16x2){(f16)u23.z, (f16)(-u23.w)};
        aim[k].h[0] = (f16x2){(f16)u01.y, (f16)u01.x};
        aim[k].h[1] = (f16x2){(f16)u01.w, (f16)u01.z};
        aim[k].h[2] = (f16x2){(f16)u23.y, (f16)u23.x};
        aim[k].h[3] = (f16x2){(f16)u23.w, (f16)u23.z};
    }
    __syncthreads();

    F8 asig;
    {
        int q = e >> 2;
        bool evenrows = (e & 3) < 2;
        #pragma unroll
        for (int j = 0; j < 8; ++j){
            int amp = 4*s + (j & 3);
            float v = 0.f;
            if (evenrows == (j < 4))
                v = ((amp >> q) & 1) ? -1.f : 1.f;
            asig.v[j] = (f16)v;
        }
    }
    F8 asigF, asigI;
    #pragma unroll
    for (int u = 0; u < 8; ++u){
        int amp = 4*s + (u & 3);
        float sg = ((amp >> ecol) & 1) ? -1.f : 1.f;
        asigF.v[u] = (f16)(u < 4 ? sg : 0.f);
        asigI.v[u] = (f16)(u >= 4 ? sg : 0.f);
    }
    F8 az;
    #pragma unroll
    for (int j = 0; j < 4; ++j){
        int k0 = s*8 + 2*j, k1 = k0 + 1;
        float v0 = (k0 < 16) ? Wd[k0*20 + (e >> 2)] : 0.f;
        float v1 = (k1 < 16) ? Wd[k1*20 + (e >> 2)] : 0.f;
        az.h[j] = (f16x2){(f16)v0, (f16)v1};
    }
    const float bdv = bd[s];
    const float4 wqs = make_float4(Wd[16*20 + s], Wd[17*20 + s],
                                   Wd[18*20 + s], Wd[19*20 + s]);

    const int b0 = blockIdx.x * 32;
    const float* xpA = x + (size_t)(b0 + e) * TSTEPS * NFEAT;
    const float* xpB = x + (size_t)(b0 + 16 + e) * TSTEPS * NFEAT;
    const float* xqA = (s < 2) ? (xpA + s*8) : xpA;
    const float* xqB = (s < 2) ? (xpB + s*8) : xpB;
    float* ypA = out + (size_t)(b0 + e) * TSTEPS * 4 + s;
    float* ypB = out + (size_t)(b0 + 16 + e) * TSTEPS * 4 + s;

    const f32x4 z4 = {0.f, 0.f, 0.f, 0.f};
    float cstA = 0.f, cstB = 0.f;
    f32x4 hvA = z4, hvB = z4;

    float4 xaA = *(const float4*)(xqA);
    float4 xbA = *(const float4*)(xqA + 4);
    float4 xaB = *(const float4*)(xqB);
    float4 xbB = *(const float4*)(xqB + 4);
    F8 bzA, bzB;
    bzA.h[0] = pkrtz(xaA.x, xaA.y); bzA.h[1] = pkrtz(xaA.z, xaA.w);
    bzA.h[2] = pkrtz(xbA.x, xbA.y); bzA.h[3] = pkrtz(xbA.z, xbA.w);
    bzB.h[0] = pkrtz(xaB.x, xaB.y); bzB.h[1] = pkrtz(xaB.z, xaB.w);
    bzB.h[2] = pkrtz(xbB.x, xbB.y); bzB.h[3] = pkrtz(xbB.z, xbB.w);
    f32x4 dzxA = __builtin_amdgcn_mfma_f32_16x16x32_f16(az.v, bzA.v, z4, 0,0,0);
    f32x4 dzxB = __builtin_amdgcn_mfma_f32_16x16x32_f16(az.v, bzB.v, z4, 0,0,0);
    xaA = *(const float4*)(xqA + NFEAT);
    xbA = *(const float4*)(xqA + NFEAT + 4);
    xaB = *(const float4*)(xqB + NFEAT);
    xbB = *(const float4*)(xqB + NFEAT + 4);

    #pragma clang loop unroll(disable)
    for (int t = 0; t < TSTEPS; ++t){
        // ---- z + activations + psi1, stage-interleaved A/B ----
        float zvalA = dzxA[0] + bdv
                    + wqs.x*hvA[0] + wqs.y*hvA[1] + wqs.z*hvA[2] + wqs.w*hvA[3];
        float zvalB = dzxB[0] + bdv
                    + wqs.x*hvB[0] + wqs.y*hvB[1] + wqs.z*hvB[2] + wqs.w*hvB[3];
        float uselA = 1.f - 2.f*frcp(__expf(zvalA) + 1.f);
        float uselB = 1.f - 2.f*frcp(__expf(zvalB) + 1.f);
        float FA0r, FA0i, FA1r, FA1i, FB0r, FB0i, FB1r, FB1i;
        factors(uselA, FA0r, FA0i, FA1r, FA1i);
        factors(uselB, FB0r, FB0i, FB1r, FB1i);
        write_F(&ldsf[BCa], e, s, FA0r, FA0i, FA1r, FA1i);
        write_F(&ldsf[BCb], e, s, FB0r, FB0i, FB1r, FB1i);
        cfence();
        F8 bpA, bpB;
        build_psi(&ldsf[BCa], e, sm1, sm2, bpA);
        build_psi(&ldsf[BCb], e, sm1, sm2, bpB);

        // ---- phase 1 U-MFMAs (A then B; independent chains) ----
        f32x4 dreA[4], dimA[4], dreB[4], dimB[4];
        #pragma unroll
        for (int k = 0; k < 4; ++k){
            dreA[k] = __builtin_amdgcn_mfma_f32_16x16x32_f16(are[k].v, bpA.v, z4, 0,0,0);
            dimA[k] = __builtin_amdgcn_mfma_f32_16x16x32_f16(aim[k].v, bpA.v, z4, 0,0,0);
        }
        #pragma unroll
        for (int k = 0; k < 4; ++k){
            dreB[k] = __builtin_amdgcn_mfma_f32_16x16x32_f16(are[k].v, bpB.v, z4, 0,0,0);
            dimB[k] = __builtin_amdgcn_mfma_f32_16x16x32_f16(aim[k].v, bpB.v, z4, 0,0,0);
        }
        F8 pb1A = pack_P(dreA[0], dimA[0], dreA[1], dimA[1]);
        F8 pb2A = pack_P(dreA[2], dimA[2], dreA[3], dimA[3]);
        F8 pb1B = pack_P(dreB[0], dimB[0], dreB[1], dimB[1]);
        F8 pb2B = pack_P(dreB[2], dimB[2], dreB[3], dimB[3]);
        f32x4 ev1A = __builtin_amdgcn_mfma_f32_16x16x32_f16(asig.v, pb1A.v, z4, 0,0,0);
        f32x4 ev2A = __builtin_amdgcn_mfma_f32_16x16x32_f16(asig.v, pb2A.v, z4, 0,0,0);
        f32x4 ev1B = __builtin_amdgcn_mfma_f32_16x16x32_f16(asig.v, pb1B.v, z4, 0,0,0);
        f32x4 ev2B = __builtin_amdgcn_mfma_f32_16x16x32_f16(asig.v, pb2B.v, z4, 0,0,0);

        // ---- pipelined z_x for t+1 (both groups) ----
        if (t + 1 < TSTEPS){
            bzA.h[0] = pkrtz(xaA.x, xaA.y); bzA.h[1] = pkrtz(xaA.z, xaA.w);
            bzA.h[2] = pkrtz(xbA.x, xbA.y); bzA.h[3] = pkrtz(xbA.z, xbA.w);
            bzB.h[0] = pkrtz(xaB.x, xaB.y); bzB.h[1] = pkrtz(xaB.z, xaB.w);
            bzB.h[2] = pkrtz(xbB.x, xbB.y); bzB.h[3] = pkrtz(xbB.z, xbB.w);
            dzxA = __builtin_amdgcn_mfma_f32_16x16x32_f16(az.v, bzA.v, z4, 0,0,0);
            dzxB = __builtin_amdgcn_mfma_f32_16x16x32_f16(az.v, bzB.v, z4, 0,0,0);
            if (t + 2 < TSTEPS){
                xaA = *(const float4*)(xqA + (t+2)*NFEAT);
                xbA = *(const float4*)(xqA + (t+2)*NFEAT + 4);
                xaB = *(const float4*)(xqB + (t+2)*NFEAT);
                xbB = *(const float4*)(xqB + (t+2)*NFEAT + 4);
            }
        }

        // ---- LSTM pointwise (own wire), A/B interleaved ----
        float fgA = sigm(ev1A[0]), igA = sigm(ev1A[2]), CgA = sigm(ev2A[0]), ogA = sigm(ev2A[2]);
        float fgB = sigm(ev1B[0]), igB = sigm(ev1B[2]), CgB = sigm(ev2B[0]), ogB = sigm(ev2B[2]);
        cstA = fgA*cstA + igA*CgA;
        cstB = fgB*cstB + igB*CgB;
        float rsA = ogA * tanh_f(cstA);
        float rsB = ogB * tanh_f(cstB);
        factors(rsA, FA0r, FA0i, FA1r, FA1i);
        factors(rsB, FB0r, FB0i, FB1r, FB1i);
        write_F(&ldsf[BCa], e, s, FA0r, FA0i, FA1r, FA1i);
        write_F(&ldsf[BCb], e, s, FB0r, FB0i, FB1r, FB1i);
        cfence();
        F8 bppA, bppB;
        build_psi(&ldsf[BCa], e, sm1, sm2, bppA);
        build_psi(&ldsf[BCb], e, sm1, sm2, bppB);

        // ---- phase 2 (A then B) ----
        f32x4 hreA = __builtin_amdgcn_mfma_f32_16x16x32_f16(are[4].v, bppA.v, z4, 0,0,0);
        f32x4 himA = __builtin_amdgcn_mfma_f32_16x16x32_f16(aim[4].v, bppA.v, z4, 0,0,0);
        f32x4 yreA = __builtin_amdgcn_mfma_f32_16x16x32_f16(are[5].v, bppA.v, z4, 0,0,0);
        f32x4 yimA = __builtin_amdgcn_mfma_f32_16x16x32_f16(aim[5].v, bppA.v, z4, 0,0,0);
        f32x4 hreB = __builtin_amdgcn_mfma_f32_16x16x32_f16(are[4].v, bppB.v, z4, 0,0,0);
        f32x4 himB = __builtin_amdgcn_mfma_f32_16x16x32_f16(aim[4].v, bppB.v, z4, 0,0,0);
        f32x4 yreB = __builtin_amdgcn_mfma_f32_16x16x32_f16(are[5].v, bppB.v, z4, 0,0,0);
        f32x4 yimB = __builtin_amdgcn_mfma_f32_16x16x32_f16(aim[5].v, bppB.v, z4, 0,0,0);
        F8 b3A = pack_P(hreA, himA, yreA, yimA);
        F8 b3B = pack_P(hreB, himB, yreB, yimB);
        hvA = __builtin_amdgcn_mfma_f32_16x16x32_f16(asigF.v, b3A.v, z4, 0,0,0);
        hvB = __builtin_amdgcn_mfma_f32_16x16x32_f16(asigF.v, b3B.v, z4, 0,0,0);
        f32x4 evYA = __builtin_amdgcn_mfma_f32_16x16x32_f16(asigI.v, b3A.v, z4, 0,0,0);
        f32x4 evYB = __builtin_amdgcn_mfma_f32_16x16x32_f16(asigI.v, b3B.v, z4, 0,0,0);

        ypA[t*4] = sel4(evYA[0], evYA[1], evYA[2], evYA[3], s);
        ypB[t*4] = sel4(evYB[0], evYB[1], evYB[2], evYB[3], s);
    }

    // final c, h for both groups
    size_t cbase = (size_t)B * TSTEPS * 4;
    out[cbase + (size_t)(b0 + e)*4 + s] = cstA;
    out[cbase + (size_t)(b0 + 16 + e)*4 + s] = cstB;
    out[cbase + (size_t)B*4 + (size_t)(b0 + e)*4 + s] = sel4(hvA[0], hvA[1], hvA[2], hvA[3], s);
    out[cbase + (size_t)B*4 + (size_t)(b0 + 16 + e)*4 + s] = sel4(hvB[0], hvB[1], hvB[2], hvB[3], s);
}

extern "C" void kernel_launch(void* const* d_in, const int* in_sizes, int n_in,
                              void* d_out, int out_size, void* d_ws, size_t ws_size,
                              hipStream_t stream) {
    const float* x   = (const float*)d_in[0];
    const float* phi = (const float*)d_in[1];
    const float* Wd  = (const float*)d_in[2];
    const float* bd  = (const float*)d_in[3];
    float* out = (float*)d_out;
    int B = in_sizes[0] / (TSTEPS * NFEAT);   // 4096
    int blocks = B / 32;                      // 128 blocks x 1 wave x 2x16 elems
    hipLaunchKernelGGL(qlstm_kernel, dim3(blocks), dim3(64), 0, stream,
                       x, phi, Wd, bd, out, B);
}

// Round 21
// 109.913 us; speedup vs baseline: 1.8486x; 1.8486x over previous
//
#include <hip/hip_runtime.h>
#include <math.h>

#define TSTEPS 128
#define NFEAT 16
#define NELEM 16   // batch elements per wave

typedef __fp16 f16;
typedef __fp16 f16x2 __attribute__((ext_vector_type(2)));
typedef __fp16 f16x8 __attribute__((ext_vector_type(8)));
typedef float f32x2 __attribute__((ext_vector_type(2)));
typedef float f32x4 __attribute__((ext_vector_type(4)));

union F8 { f16x8 v; f16x2 h[4]; };

__device__ __forceinline__ float frcp(float x){ return __builtin_amdgcn_rcpf(x); }
__device__ __forceinline__ float frsq(float x){ return __builtin_amdgcn_rsqf(x); }
__device__ __forceinline__ float bperm(int addr, float v){
    return __int_as_float(__builtin_amdgcn_ds_bpermute(addr, __float_as_int(v)));
}
__device__ __forceinline__ f16x2 pkrtz(float a, float b){
    return __builtin_amdgcn_cvt_pkrtz(a, b);
}
__device__ __forceinline__ float dpp_xor1(float v){
    return __int_as_float(__builtin_amdgcn_update_dpp(0, __float_as_int(v), 0xB1, 0xF, 0xF, true));
}
__device__ __forceinline__ float dpp_xor2(float v){
    return __int_as_float(__builtin_amdgcn_update_dpp(0, __float_as_int(v), 0x4E, 0xF, 0xF, true));
}
__device__ __forceinline__ float swz_xor4(float v){
    return __int_as_float(__builtin_amdgcn_ds_swizzle(__float_as_int(v), 0x101F));
}
__device__ __forceinline__ float swz_xor8(float v){
    return __int_as_float(__builtin_amdgcn_ds_swizzle(__float_as_int(v), 0x201F));
}
template<int MASK> __device__ __forceinline__ float pshfl(float v){
    if constexpr (MASK == 1) return dpp_xor1(v);
    else if constexpr (MASK == 2) return dpp_xor2(v);
    else if constexpr (MASK == 4) return swz_xor4(v);
    else return swz_xor8(v);
}
__device__ __forceinline__ void cfence(){ __asm__ __volatile__("" ::: "memory"); }

__device__ __forceinline__ float sigm(float x){ return frcp(1.f + __expf(-x)); }
__device__ __forceinline__ float tanh_f(float x){ return 1.f - 2.f * frcp(__expf(2.f*x) + 1.f); }

// packed complex multiply: (a.x*b.x - a.y*b.y, a.x*b.y + a.y*b.x)
// maps to v_pk_mul_f32 + v_pk_fma_f32 (swap/neg via op_sel modifiers)
__device__ __forceinline__ f32x2 cmul(f32x2 a, f32x2 b){
    f32x2 bs = {b.y, b.x};
    f32x2 ar = {a.x, a.x};
    f32x2 ai = {-a.y, a.y};
    return ar*b + ai*bs;
}

// merged RZ*RY*RX on wire I (prologue / U-construction only)
template<int I>
__device__ __forceinline__ void gate_step(float &re, float &im,
                                          const float* gt, int ai, int loff){
    const float4 g = *(const float4*)((const char*)gt + ai + loff);
    float pre = pshfl<(1 << I)>(re);
    float pim = pshfl<(1 << I)>(im);
    float nre = g.x*re - g.y*im + g.z*pre - g.w*pim;
    float nim = g.x*im + g.y*re + g.z*pim + g.w*pre;
    re = nre; im = nim;
}

// fused factor products: F(0) = (c1c2, -c1s2), F(1) = (s1c2, s1s2)
// for angles atan(u) (RY) and atan(u^2) (RZ) -- 3 trans instead of 4
__device__ __forceinline__ void factors(float u, float &F0r, float &F0i,
                                        float &F1r, float &F1i){
    float u2  = u * u;
    float ca1 = frsq(1.f + u2);          // cos(atan u)
    float ca2 = frsq(1.f + u2*u2);       // cos(atan u^2)
    float x1  = (1.f + ca1) * 0.5f;      // cos^2 of half-angles
    float x2  = (1.f + ca2) * 0.5f;
    float x12 = x1 * x2;
    float t   = frsq(x12);
    float a1  = u  * ca1 * 0.5f;
    float a2  = u2 * ca2 * 0.5f;
    F0r = x12 * t;                       // c1*c2
    F0i = -(a2 * x1 * t);                // -(c1*s2)
    F1r = a1 * x2 * t;                   // s1*c2
    F1i = a1 * a2 * t;                   // s1*s2
}

// lane (e,s) emits complex factors F_s(0), F_s(1) of its wire into LDS
__device__ __forceinline__ void write_F(float* bc, int e, int s,
                                        float F0r, float F0i, float F1r, float F1i){
    float4 w;
    w.x = F0r; w.y = F0i; w.z = F1r; w.w = F1i;
    *(float4*)(bc + e*20 + s*4) = w;
}

// lane (e,s) builds its 4 amplitudes a=4s..4s+3 of elem e's init state (B-fragment)
// complex arithmetic via packed-f32 (v_pk_mul/v_pk_fma candidates)
__device__ __forceinline__ void build_psi(const float* bc, int e, int sm1, int sm2,
                                          F8 &bp){
    const float4 w0 = *(const float4*)(bc + e*20);               // wire0: F(0),F(1)
    const float4 w1 = *(const float4*)(bc + e*20 + 4);           // wire1
    const f32x2 F2 = *(const f32x2*)(bc + e*20 + 8  + sm1*2);    // F_2(s&1)
    const f32x2 F3 = *(const f32x2*)(bc + e*20 + 12 + sm2*2);    // F_3(s>>1)
    f32x2 w00 = {w0.x, w0.y}, w01 = {w0.z, w0.w};
    f32x2 w10 = {w1.x, w1.y}, w11 = {w1.z, w1.w};
    f32x2 pre = cmul(F2, F3);                                    // prefix
    f32x2 P0 = cmul(pre, w10);                                   // prefix*F1(0)
    f32x2 P1 = cmul(pre, w11);                                   // prefix*F1(1)
    f32x2 a0 = cmul(P0, w00);
    f32x2 a1 = cmul(P0, w01);
    f32x2 a2 = cmul(P1, w00);
    f32x2 a3 = cmul(P1, w01);
    bp.h[0] = pkrtz(a0.x, a0.y);
    bp.h[1] = pkrtz(a1.x, a1.y);
    bp.h[2] = pkrtz(a2.x, a2.y);
    bp.h[3] = pkrtz(a3.x, a3.y);
}

// pack two circuits' probabilities via packed-f32 vector math:
// slot 8s+u: u<4 -> even amp 4s+u, u>=4 -> odd amp 4s+u-4
__device__ __forceinline__ F8 pack_P(const f32x4 &reE, const f32x4 &imE,
                                     const f32x4 &reO, const f32x4 &imO){
    f32x4 pE = reE*reE + imE*imE;
    f32x4 pO = reO*reO + imO*imO;
    F8 b;
    b.h[0] = pkrtz(pE[0], pE[1]);
    b.h[1] = pkrtz(pE[2], pE[3]);
    b.h[2] = pkrtz(pO[0], pO[1]);
    b.h[3] = pkrtz(pO[2], pO[3]);
    return b;
}

__device__ __forceinline__ float sel4(float a0, float a1, float a2, float a3, int s){
    float lo = (s & 1) ? a1 : a0;
    float hi = (s & 1) ? a3 : a2;
    return (s & 2) ? hi : lo;
}

__global__ void __launch_bounds__(64, 1) qlstm_kernel(
    const float* __restrict__ x, const float* __restrict__ phi,
    const float* __restrict__ Wd, const float* __restrict__ bd,
    float* __restrict__ out, int B)
{
    // gtab: 8 rows (l,i) x 48 floats (12 entries x {Ar,Ai,Br,Bi}) -- 192B stride
    __shared__ __align__(16) float gtab[384];
    __shared__ __align__(16) float ldsf[3072];
    const int UBo = 0;      // 3072 floats: U[k][m][c] complex at k*512+m*32+c*2
    const int BCo = 0;      // factor pairs alias the U region (U read only in prologue)

    const int tid  = threadIdx.x;
    const int lane = tid & 63;
    const int m    = lane & 15;
    const int grp  = lane >> 4;

    // ---------------- prologue: merged-gate table ----------------------------
    for (int idx = tid; idx < 96; idx += 64){
        int i = idx & 3, l = (idx >> 2) & 1, bb = (idx >> 3) & 1, k = idx >> 4;
        const float* pp = phi + (k*2 + l)*12 + 3*i;
        float ca, sa, cb, sb, cg, sg;
        __sincosf(0.5f*pp[0], &sa, &ca);
        __sincosf(0.5f*pp[1], &sb, &cb);
        __sincosf(0.5f*pp[2], &sg, &cg);
        float Ar, Ai, Br, Bi;
        if (bb == 0){
            float m00r = cb*ca,  m00i = sb*sa;
            float m01r = -sb*ca, m01i = -cb*sa;
            Ar = m00r*cg + m00i*sg;  Ai = m00i*cg - m00r*sg;
            Br = m01r*cg + m01i*sg;  Bi = m01i*cg - m01r*sg;
        } else {
            float m10r = sb*ca, m10i = -cb*sa;
            float m11r = cb*ca, m11i = -sb*sa;
            Ar = m11r*cg - m11i*sg;  Ai = m11i*cg + m11r*sg;
            Br = m10r*cg - m10i*sg;  Bi = m10i*cg + m10r*sg;
        }
        float* dst = gtab + (l*4 + i)*48 + (k*2 + bb)*4;
        dst[0] = Ar; dst[1] = Ai; dst[2] = Br; dst[3] = Bi;
    }
    __syncthreads();

    // CNOT-block permutation P^{-1}(m) and mid-circuit bpermute address
    const int n0 = m & 1, n1 = (m >> 1) & 1, n2 = (m >> 2) & 1, n3 = (m >> 3) & 1;
    const int pm = (n0^n1^n2) | ((n0^n2^n3) << 1) | ((n0^n1^n3) << 2) | ((n0^n1) << 3);
    const int bpaddr = ((lane & 48) | pm) * 4;

    // ---------------- prologue: build U_k columns via shuffle circuit --------
    for (int k = 0; k < 6; ++k){
        int ga0 = 0*192 + k*32 + ((m >> 0) & 1)*16;
        int ga1 = 1*192 + k*32 + ((m >> 1) & 1)*16;
        int ga2 = 2*192 + k*32 + ((m >> 2) & 1)*16;
        int ga3 = 3*192 + k*32 + ((m >> 3) & 1)*16;
        for (int cb = 0; cb < 4; ++cb){
            int c = cb*4 + grp;
            float re = (pm == c) ? 1.f : 0.f;   // P folded into columns
            float im = 0.f;
            gate_step<0>(re, im, gtab, ga0, 0);   gate_step<1>(re, im, gtab, ga1, 0);
            gate_step<2>(re, im, gtab, ga2, 0);   gate_step<3>(re, im, gtab, ga3, 0);
            re = bperm(bpaddr, re);
            im = bperm(bpaddr, im);
            gate_step<0>(re, im, gtab, ga0, 768); gate_step<1>(re, im, gtab, ga1, 768);
            gate_step<2>(re, im, gtab, ga2, 768); gate_step<3>(re, im, gtab, ga3, 768);
            float2* dst = (float2*)&ldsf[UBo + k*512 + m*32 + c*2];
            *dst = make_float2(re, im);
        }
    }
    __syncthreads();

    // ---------------- main layout: lane = (e, s) -----------------------------
    const int e = lane & 15;       // batch element (A row, B/D col)
    const int s = lane >> 4;       // own wire / k-quarter
    const int sm1 = s & 1, sm2 = s >> 1;
    const int ecol = e & 3;

    // A-fragments of U_k (re/im) -- loaded once, pinned by the aliasing stores
    F8 are[6], aim[6];
    #pragma unroll
    for (int k = 0; k < 6; ++k){
        const float* ub = &ldsf[UBo + k*512 + e*32 + s*8];
        float4 u01 = *(const float4*)ub;         // amps 4s, 4s+1 (re,im)
        float4 u23 = *(const float4*)(ub + 4);   // amps 4s+2, 4s+3
        are[k].h[0] = (f16x2){(f16)u01.x, (f16)(-u01.y)};
        are[k].h[1] = (f16x2){(f16)u01.z, (f16)(-u01.w)};
        are[k].h[2] = (f16x2){(f16)u23.x, (f16)(-u23.y)};
        are[k].h[3] = (f16x2){(f16)u23.z, (f16)(-u23.w)};
        aim[k].h[0] = (f16x2){(f16)u01.y, (f16)u01.x};
        aim[k].h[1] = (f16x2){(f16)u01.w, (f16)u01.z};
        aim[k].h[2] = (f16x2){(f16)u23.y, (f16)u23.x};
        aim[k].h[3] = (f16x2){(f16)u23.w, (f16)u23.z};
    }
    __syncthreads();   // all lanes done reading U before anyone overwrites it

    // R8-style packed sign fragment: lane (e,s) output regs 0,1 = ev_s(even ckt), 2,3 = ev_s(odd)
    F8 asig;
    {
        int q = e >> 2;
        bool evenrows = (e & 3) < 2;
        #pragma unroll
        for (int j = 0; j < 8; ++j){
            int amp = 4*s + (j & 3);
            float v = 0.f;
            if (evenrows == (j < 4))
                v = ((amp >> q) & 1) ? -1.f : 1.f;
            asig.v[j] = (f16)v;
        }
    }
    // all-wire sign fragments: evX[j] = ev of wire j (even / odd circuit)
    F8 asigF, asigI;
    #pragma unroll
    for (int u = 0; u < 8; ++u){
        int amp = 4*s + (u & 3);
        float sg = ((amp >> ecol) & 1) ? -1.f : 1.f;
        asigF.v[u] = (f16)(u < 4 ? sg : 0.f);
        asigI.v[u] = (f16)(u >= 4 ? sg : 0.f);
    }

    // A_z (x-only): rows 4q..4q+3 all = Wd column q (k<16) -> dzx[0] = z_x(own wire)
    F8 az;
    #pragma unroll
    for (int j = 0; j < 4; ++j){
        int k0 = s*8 + 2*j, k1 = k0 + 1;
        float v0 = (k0 < 16) ? Wd[k0*20 + (e >> 2)] : 0.f;
        float v1 = (k1 < 16) ? Wd[k1*20 + (e >> 2)] : 0.f;
        az.h[j] = (f16x2){(f16)v0, (f16)v1};
    }
    const float bdv = bd[s];
    // Wd_h column s in f32: z_h,s = sum_q Wd[16+q][s] * h_q
    const float4 wqs = make_float4(Wd[16*20 + s], Wd[17*20 + s],
                                   Wd[18*20 + s], Wd[19*20 + s]);

    const int b0 = blockIdx.x * NELEM;
    const float* xp = x + (size_t)(b0 + e) * TSTEPS * NFEAT;
    // lanes s>=2 feed only k-slots >=16 where az rows are 0 -> content don't-care
    const float* xq = (s < 2) ? (xp + s*8) : xp;
    float* yp = out + (size_t)(b0 + e) * TSTEPS * 4 + s;

    const f32x4 z4 = {0.f, 0.f, 0.f, 0.f};
    float cst = 0.f;
    f32x4 hv = z4;                  // all-wire h state (f32, replicated across s)

    // x prefetch + pipelined z_x MFMA for t=0
    float4 xa = *(const float4*)(xq);
    float4 xb = *(const float4*)(xq + 4);
    F8 bz;
    bz.h[0] = pkrtz(xa.x, xa.y);
    bz.h[1] = pkrtz(xa.z, xa.w);
    bz.h[2] = pkrtz(xb.x, xb.y);
    bz.h[3] = pkrtz(xb.z, xb.w);
    f32x4 dzx = __builtin_amdgcn_mfma_f32_16x16x32_f16(az.v, bz.v, z4, 0, 0, 0);
    xa = *(const float4*)(xq + NFEAT);
    xb = *(const float4*)(xq + NFEAT + 4);

    #pragma clang loop unroll(disable)
    for (int t = 0; t < TSTEPS; ++t){
        // ---- z (own wire) = z_x (pipelined MFMA) + Wd_h^T h (f32 VALU) + bd ----
        float zval = dzx[0] + bdv
                   + wqs.x*hv[0] + wqs.y*hv[1] + wqs.z*hv[2] + wqs.w*hv[3];
        float usel = 1.f - 2.f*frcp(__expf(zval) + 1.f);
        float F0r, F0i, F1r, F1i;
        factors(usel, F0r, F0i, F1r, F1i);
        write_F(&ldsf[BCo], e, s, F0r, F0i, F1r, F1i);
        cfence();
        F8 bp;
        build_psi(&ldsf[BCo], e, sm1, sm2, bp);

        // ---- phase 1: f,i,Cg,o = 8 U-MFMAs + 2 EV-MFMAs (packed, own wire) ----
        f32x4 dre[4], dim4[4];
        #pragma unroll
        for (int k = 0; k < 4; ++k){
            dre[k]  = __builtin_amdgcn_mfma_f32_16x16x32_f16(are[k].v, bp.v, z4, 0,0,0);
            dim4[k] = __builtin_amdgcn_mfma_f32_16x16x32_f16(aim[k].v, bp.v, z4, 0,0,0);
        }
        F8 pb1 = pack_P(dre[0], dim4[0], dre[1], dim4[1]);   // f (even), i (odd)
        F8 pb2 = pack_P(dre[2], dim4[2], dre[3], dim4[3]);   // Cg, o
        f32x4 ev1 = __builtin_amdgcn_mfma_f32_16x16x32_f16(asig.v, pb1.v, z4, 0,0,0);
        f32x4 ev2 = __builtin_amdgcn_mfma_f32_16x16x32_f16(asig.v, pb2.v, z4, 0,0,0);

        // ---- pipelined z_x for t+1 ----
        if (t + 1 < TSTEPS){
            bz.h[0] = pkrtz(xa.x, xa.y);
            bz.h[1] = pkrtz(xa.z, xa.w);
            bz.h[2] = pkrtz(xb.x, xb.y);
            bz.h[3] = pkrtz(xb.z, xb.w);
            dzx = __builtin_amdgcn_mfma_f32_16x16x32_f16(az.v, bz.v, z4, 0,0,0);
            if (t + 2 < TSTEPS){
                xa = *(const float4*)(xq + (t+2)*NFEAT);
                xb = *(const float4*)(xq + (t+2)*NFEAT + 4);
            }
        }

        // ---- LSTM pointwise (own wire s only) ----
        float fg = sigm(ev1[0]), ig = sigm(ev1[2]), Cg = sigm(ev2[0]), og = sigm(ev2[2]);
        cst = fg*cst + ig*Cg;
        float rs = og * tanh_f(cst);
        factors(rs, F0r, F0i, F1r, F1i);
        write_F(&ldsf[BCo], e, s, F0r, F0i, F1r, F1i);
        cfence();
        F8 bpp;
        build_psi(&ldsf[BCo], e, sm1, sm2, bpp);

        // ---- phase 2: h (k=4), y (k=5) = 4 U-MFMAs + 2 EV-MFMAs ----
        f32x4 hre = __builtin_amdgcn_mfma_f32_16x16x32_f16(are[4].v, bpp.v, z4, 0,0,0);
        f32x4 him = __builtin_amdgcn_mfma_f32_16x16x32_f16(aim[4].v, bpp.v, z4, 0,0,0);
        f32x4 yre = __builtin_amdgcn_mfma_f32_16x16x32_f16(are[5].v, bpp.v, z4, 0,0,0);
        f32x4 yim = __builtin_amdgcn_mfma_f32_16x16x32_f16(aim[5].v, bpp.v, z4, 0,0,0);
        F8 b3 = pack_P(hre, him, yre, yim);                 // h (even), y (odd)
        hv = __builtin_amdgcn_mfma_f32_16x16x32_f16(asigF.v, b3.v, z4, 0,0,0);  // all-wire h
        f32x4 evY = __builtin_amdgcn_mfma_f32_16x16x32_f16(asigI.v, b3.v, z4, 0,0,0);

        // ---- y scatter (own wire, off critical path) ----
        yp[t*4] = sel4(evY[0], evY[1], evY[2], evY[3], s);
    }

    // final c (own wire), h (select own wire from all-wire state)
    size_t cbase = (size_t)B * TSTEPS * 4;
    out[cbase + (size_t)(b0 + e)*4 + s] = cst;
    out[cbase + (size_t)B*4 + (size_t)(b0 + e)*4 + s] = sel4(hv[0], hv[1], hv[2], hv[3], s);
}

extern "C" void kernel_launch(void* const* d_in, const int* in_sizes, int n_in,
                              void* d_out, int out_size, void* d_ws, size_t ws_size,
                              hipStream_t stream) {
    const float* x   = (const float*)d_in[0];
    const float* phi = (const float*)d_in[1];
    const float* Wd  = (const float*)d_in[2];
    const float* bd  = (const float*)d_in[3];
    float* out = (float*)d_out;
    int B = in_sizes[0] / (TSTEPS * NFEAT);   // 4096
    int blocks = B / NELEM;                   // 256 blocks x 1 wave x 16 elems
    hipLaunchKernelGGL(qlstm_kernel, dim3(blocks), dim3(64), 0, stream,
                       x, phi, Wd, bd, out, B);
}